// Round 1
// baseline (432.099 us; speedup 1.0000x reference)
//
#include <hip/hip_runtime.h>
#include <math.h>

#define N_NODES 4096
#define F_IN    512
#define E0_EDGES 12288
#define E_TOT   16384   // E0 + N self loops
#define C_CLS   16
#define HID1    32
#define HID2    16
#define LPA_ITERS 5

// ---------------------------------------------------------------------------
// ew_raw[row] = sum_j W_edge[row][j] + b_edge[row]
// One block per row: 16384 floats = 4096 float4 per row, 256 threads.
__global__ void row_sum_kernel(const float* __restrict__ W,
                               const float* __restrict__ b,
                               float* __restrict__ ew_raw) {
    const int row = blockIdx.x;
    const float4* p = (const float4*)(W + (size_t)row * E_TOT);
    float s = 0.f;
    #pragma unroll 4
    for (int i = threadIdx.x; i < E_TOT / 4; i += 256) {
        float4 v = p[i];
        s += (v.x + v.y) + (v.z + v.w);
    }
    // wave reduce (64 lanes)
    #pragma unroll
    for (int off = 32; off > 0; off >>= 1) s += __shfl_down(s, off, 64);
    __shared__ float sm[4];
    const int lane = threadIdx.x & 63, wave = threadIdx.x >> 6;
    if (lane == 0) sm[wave] = s;
    __syncthreads();
    if (threadIdx.x == 0) {
        ew_raw[row] = (sm[0] + sm[1]) + (sm[2] + sm[3]) + b[row];
    }
}

// deg[col[e]] += ew_raw[e]
__global__ void deg_kernel(const int* __restrict__ ei,
                           const float* __restrict__ ew_raw,
                           float* __restrict__ deg) {
    const int e = blockIdx.x * blockDim.x + threadIdx.x;
    if (e >= E_TOT) return;
    const int col = (e < E0_EDGES) ? ei[E0_EDGES + e] : (e - E0_EDGES);
    atomicAdd(&deg[col], ew_raw[e]);
}

// ew[e] = (isinf(deg[row[e]]) ? 0 : deg[row[e]]) * ew_raw[e]
__global__ void scale_ew_kernel(const int* __restrict__ ei,
                                const float* __restrict__ ew_raw,
                                const float* __restrict__ deg,
                                float* __restrict__ ew) {
    const int e = blockIdx.x * blockDim.x + threadIdx.x;
    if (e >= E_TOT) return;
    const int row = (e < E0_EDGES) ? ei[e] : (e - E0_EDGES);
    float d = deg[row];
    if (isinf(d)) d = 0.f;
    ew[e] = d * ew_raw[e];
}

// out[n][j] = b[j] + sum_k f(in[n][k]) * W[k][j],  f = relu if relu_in
__global__ void dense_kernel(const float* __restrict__ in,
                             const float* __restrict__ W,
                             const float* __restrict__ b,
                             float* __restrict__ out,
                             int K, int M, int relu_in) {
    const int idx = blockIdx.x * blockDim.x + threadIdx.x;
    if (idx >= N_NODES * M) return;
    const int n = idx / M, j = idx % M;
    const float* xr = in + (size_t)n * K;
    float acc = b[j];
    for (int k = 0; k < K; ++k) {
        float v = xr[k];
        if (relu_in) v = fmaxf(v, 0.f);
        acc = fmaf(v, W[k * M + j], acc);
    }
    out[idx] = acc;
}

// dst[col[e]][f] += ew[e] * src[row[e]][f]   (dst pre-zeroed)
__global__ void agg_kernel(const int* __restrict__ ei,
                           const float* __restrict__ ew,
                           const float* __restrict__ src,
                           float* __restrict__ dst, int F) {
    const int idx = blockIdx.x * blockDim.x + threadIdx.x;
    if (idx >= E_TOT * F) return;
    const int e = idx / F, f = idx % F;
    const int row = (e < E0_EDGES) ? ei[e] : (e - E0_EDGES);
    const int col = (e < E0_EDGES) ? ei[E0_EDGES + e] : (e - E0_EDGES);
    atomicAdd(&dst[(size_t)col * F + f], ew[e] * src[(size_t)row * F + f]);
}

// yh[n][c] = (mask[n] && y[n]==c) ? 1 : 0
__global__ void onehot_kernel(const int* __restrict__ y,
                              const int* __restrict__ mask,
                              float* __restrict__ yh) {
    const int idx = blockIdx.x * blockDim.x + threadIdx.x;
    if (idx >= N_NODES * C_CLS) return;
    const int n = idx / C_CLS, c = idx % C_CLS;
    yh[idx] = (mask[n] != 0 && y[n] == c) ? 1.f : 0.f;
}

// out[n][:] = in[n][:] - logsumexp(in[n][:]) over M=16 columns
__global__ void log_softmax_kernel(const float* __restrict__ in,
                                   float* __restrict__ out, int M) {
    const int n = blockIdx.x * blockDim.x + threadIdx.x;
    if (n >= N_NODES) return;
    const float* r = in + (size_t)n * M;
    float mx = r[0];
    for (int j = 1; j < M; ++j) mx = fmaxf(mx, r[j]);
    float s = 0.f;
    for (int j = 0; j < M; ++j) s += expf(r[j] - mx);
    const float l = logf(s) + mx;
    for (int j = 0; j < M; ++j) out[(size_t)n * M + j] = r[j] - l;
}

extern "C" void kernel_launch(void* const* d_in, const int* in_sizes, int n_in,
                              void* d_out, int out_size, void* d_ws, size_t ws_size,
                              hipStream_t stream) {
    const float* x      = (const float*)d_in[0];
    const int*   ei     = (const int*)d_in[1];   // [2*E0] flat: rows then cols
    const int*   y      = (const int*)d_in[2];
    const int*   mask   = (const int*)d_in[3];
    const float* W_edge = (const float*)d_in[4];
    const float* b_edge = (const float*)d_in[5];
    const float* W1 = (const float*)d_in[6];  const float* b1 = (const float*)d_in[7];
    const float* W2 = (const float*)d_in[8];  const float* b2 = (const float*)d_in[9];
    const float* W3 = (const float*)d_in[10]; const float* b3 = (const float*)d_in[11];
    const float* W4 = (const float*)d_in[12]; const float* b4 = (const float*)d_in[13];
    float* out = (float*)d_out;

    // workspace layout (floats)
    float* ws     = (float*)d_ws;
    float* ew_raw = ws;                       // E_TOT
    float* ew     = ew_raw + E_TOT;           // E_TOT
    float* deg    = ew + E_TOT;               // N
    float* bufA   = deg + N_NODES;            // N*32
    float* bufB   = bufA + N_NODES * HID1;    // N*32
    float* yhA    = bufB + N_NODES * HID1;    // N*16
    float* yhB    = yhA + N_NODES * C_CLS;    // N*16

    const int T = 256;
    const int eBlocks = (E_TOT + T - 1) / T;

    // --- edge weights ---
    row_sum_kernel<<<E_TOT, T, 0, stream>>>(W_edge, b_edge, ew_raw);
    hipMemsetAsync(deg, 0, N_NODES * sizeof(float), stream);
    deg_kernel<<<eBlocks, T, 0, stream>>>(ei, ew_raw, deg);
    scale_ew_kernel<<<eBlocks, T, 0, stream>>>(ei, ew_raw, deg, ew);

    // --- GCN layers ---
    // L1: pre = x@W1+b1 (K=512,M=32), agg
    dense_kernel<<<(N_NODES * HID1 + T - 1) / T, T, 0, stream>>>(x, W1, b1, bufA, F_IN, HID1, 0);
    hipMemsetAsync(bufB, 0, N_NODES * HID1 * sizeof(float), stream);
    agg_kernel<<<(E_TOT * HID1 + T - 1) / T, T, 0, stream>>>(ei, ew, bufA, bufB, HID1);
    // L2: pre = relu(bufB)@W2+b2 (K=32,M=16)
    dense_kernel<<<(N_NODES * HID2 + T - 1) / T, T, 0, stream>>>(bufB, W2, b2, bufA, HID1, HID2, 1);
    hipMemsetAsync(bufB, 0, N_NODES * HID2 * sizeof(float), stream);
    agg_kernel<<<(E_TOT * HID2 + T - 1) / T, T, 0, stream>>>(ei, ew, bufA, bufB, HID2);
    // L3
    dense_kernel<<<(N_NODES * HID2 + T - 1) / T, T, 0, stream>>>(bufB, W3, b3, bufA, HID2, HID2, 1);
    hipMemsetAsync(bufB, 0, N_NODES * HID2 * sizeof(float), stream);
    agg_kernel<<<(E_TOT * HID2 + T - 1) / T, T, 0, stream>>>(ei, ew, bufA, bufB, HID2);
    // L4 (no relu on output)
    dense_kernel<<<(N_NODES * C_CLS + T - 1) / T, T, 0, stream>>>(bufB, W4, b4, bufA, HID2, C_CLS, 1);
    hipMemsetAsync(bufB, 0, N_NODES * C_CLS * sizeof(float), stream);
    agg_kernel<<<(E_TOT * C_CLS + T - 1) / T, T, 0, stream>>>(ei, ew, bufA, bufB, C_CLS);
    // out0 = log_softmax(h)
    log_softmax_kernel<<<(N_NODES + T - 1) / T, T, 0, stream>>>(bufB, out, C_CLS);

    // --- LPA ---
    onehot_kernel<<<(N_NODES * C_CLS + T - 1) / T, T, 0, stream>>>(y, mask, yhA);
    float* src = yhA; float* dst = yhB;
    for (int it = 0; it < LPA_ITERS; ++it) {
        hipMemsetAsync(dst, 0, N_NODES * C_CLS * sizeof(float), stream);
        agg_kernel<<<(E_TOT * C_CLS + T - 1) / T, T, 0, stream>>>(ei, ew, src, dst, C_CLS);
        float* tmp = src; src = dst; dst = tmp;
    }
    // out1 = log_softmax(yh)
    log_softmax_kernel<<<(N_NODES + T - 1) / T, T, 0, stream>>>(src, out + (size_t)N_NODES * C_CLS, C_CLS);
}

// Round 2
// 281.477 us; speedup vs baseline: 1.5351x; 1.5351x over previous
//
#include <hip/hip_runtime.h>
#include <math.h>

#define N_NODES 4096
#define F_IN    512
#define E0_EDGES 12288
#define E_TOT   16384   // E0 + N self loops
#define C_CLS   16
#define HID1    32
#define HID2    16

// ---------------------------------------------------------------------------
// ew_raw[row] = sum_j W_edge[row][j] + b_edge[row]  (reads 1.07 GB — the floor)
__global__ __launch_bounds__(256) void row_sum_kernel(const float* __restrict__ W,
                               const float* __restrict__ b,
                               float* __restrict__ ew_raw) {
    const int row = blockIdx.x;
    const float4* p = (const float4*)(W + (size_t)row * E_TOT);
    float s = 0.f;
    #pragma unroll 4
    for (int i = threadIdx.x; i < E_TOT / 4; i += 256) {
        float4 v = p[i];
        s += (v.x + v.y) + (v.z + v.w);
    }
    #pragma unroll
    for (int off = 32; off > 0; off >>= 1) s += __shfl_down(s, off, 64);
    __shared__ float sm[4];
    const int lane = threadIdx.x & 63, wave = threadIdx.x >> 6;
    if (lane == 0) sm[wave] = s;
    __syncthreads();
    if (threadIdx.x == 0) {
        ew_raw[row] = (sm[0] + sm[1]) + (sm[2] + sm[3]) + b[row];
    }
}

// ---------------------------------------------------------------------------
// CSR-by-col build: count -> scan -> fill
__global__ __launch_bounds__(256) void csr_count_kernel(const int* __restrict__ ei,
                                                        int* __restrict__ cnt) {
    const int e = blockIdx.x * 256 + threadIdx.x;
    if (e >= E_TOT) return;
    const int col = (e < E0_EDGES) ? ei[E0_EDGES + e] : (e - E0_EDGES);
    atomicAdd(&cnt[col], 1);
}

// single block: exclusive scan of cnt[4096] -> rowptr[4097]; also zero fillcnt
__global__ __launch_bounds__(256) void scan_kernel(const int* __restrict__ cnt,
                                                   int* __restrict__ rowptr,
                                                   int* __restrict__ fillcnt) {
    __shared__ int part[256];
    const int t = threadIdx.x;
    const int base = t * 16;
    int local[16];
    int s = 0;
    #pragma unroll
    for (int i = 0; i < 16; ++i) { local[i] = s; s += cnt[base + i]; }
    part[t] = s;
    __syncthreads();
    for (int off = 1; off < 256; off <<= 1) {
        int v = (t >= off) ? part[t - off] : 0;
        __syncthreads();
        if (t >= off) part[t] += v;
        __syncthreads();
    }
    const int prev = (t == 0) ? 0 : part[t - 1];
    #pragma unroll
    for (int i = 0; i < 16; ++i) rowptr[base + i] = prev + local[i];
    if (t == 255) rowptr[N_NODES] = part[255];
    for (int i = t; i < N_NODES; i += 256) fillcnt[i] = 0;
}

__global__ __launch_bounds__(256) void csr_fill_kernel(const int* __restrict__ ei,
                                                       const int* __restrict__ rowptr,
                                                       int* __restrict__ fillcnt,
                                                       int* __restrict__ srow,
                                                       int* __restrict__ eid,
                                                       int* __restrict__ pos) {
    const int e = blockIdx.x * 256 + threadIdx.x;
    if (e >= E_TOT) return;
    const int rowe = (e < E0_EDGES) ? ei[e] : (e - E0_EDGES);
    const int col  = (e < E0_EDGES) ? ei[E0_EDGES + e] : (e - E0_EDGES);
    const int j = rowptr[col] + atomicAdd(&fillcnt[col], 1);
    srow[j] = rowe;
    eid[j]  = e;
    pos[e]  = j;
}

// deg[n] = sum of ew_raw over incoming edges (inf masked)
__global__ __launch_bounds__(256) void deg_kernel(const float* __restrict__ ew_raw,
                                                  const int* __restrict__ rowptr,
                                                  const int* __restrict__ eid,
                                                  float* __restrict__ deg) {
    const int n = blockIdx.x * 256 + threadIdx.x;
    if (n >= N_NODES) return;
    float s = 0.f;
    const int e0 = rowptr[n], e1 = rowptr[n + 1];
    for (int j = e0; j < e1; ++j) s += ew_raw[eid[j]];
    deg[n] = isinf(s) ? 0.f : s;
}

// ew_s[pos[e]] = deg[row[e]] * ew_raw[e]   (CSR-ordered scaled edge weight)
__global__ __launch_bounds__(256) void scale_kernel(const int* __restrict__ ei,
                                                    const float* __restrict__ ew_raw,
                                                    const float* __restrict__ deg,
                                                    const int* __restrict__ pos,
                                                    float* __restrict__ ew_s) {
    const int e = blockIdx.x * 256 + threadIdx.x;
    if (e >= E_TOT) return;
    const int rowe = (e < E0_EDGES) ? ei[e] : (e - E0_EDGES);
    ew_s[pos[e]] = deg[rowe] * ew_raw[e];
}

// ---------------------------------------------------------------------------
// dense1: out[n][f] = b[f] + sum_k x[n][k]*W[k][f], K=512, F=32
__global__ __launch_bounds__(256) void dense1_kernel(const float* __restrict__ x,
                                                     const float* __restrict__ W,
                                                     const float* __restrict__ b,
                                                     float* __restrict__ out) {
    const int idx = blockIdx.x * 256 + threadIdx.x;
    const int n = idx >> 5, f = idx & 31;
    const float* xr = x + (size_t)n * F_IN;
    float acc = b[f];
    #pragma unroll 8
    for (int k = 0; k < F_IN; ++k) acc = fmaf(xr[k], W[k * HID1 + f], acc);
    out[idx] = acc;
}

// fused: acc = gather-agg(src, FA wide); [relu]; [dense FA->FO via LDS] or
// [log_softmax across 16 lanes] or plain store.
template <int FA, int FO, bool RELU, bool DENSE, bool SOFTMAX>
__global__ __launch_bounds__(256) void layer_kernel(const float* __restrict__ src,
                                                    const int* __restrict__ rowptr,
                                                    const int* __restrict__ srow,
                                                    const float* __restrict__ ew_s,
                                                    const float* __restrict__ W,
                                                    const float* __restrict__ b,
                                                    float* __restrict__ dst) {
    constexpr int G = 256 / FA;
    const int t = threadIdx.x;
    const int nl = t / FA, f = t % FA;
    const int n = blockIdx.x * G + nl;
    float acc = 0.f;
    const int e0 = rowptr[n], e1 = rowptr[n + 1];
    for (int j = e0; j < e1; ++j)
        acc = fmaf(ew_s[j], src[srow[j] * FA + f], acc);
    if constexpr (RELU) acc = fmaxf(acc, 0.f);
    if constexpr (DENSE) {
        __shared__ float sm[G][FA];
        sm[nl][f] = acc;
        __syncthreads();
        if (f < FO) {
            float o = b[f];
            #pragma unroll
            for (int k = 0; k < FA; ++k) o = fmaf(sm[nl][k], W[k * FO + f], o);
            dst[n * FO + f] = o;
        }
    } else if constexpr (SOFTMAX) {
        float mx = acc;
        #pragma unroll
        for (int off = 8; off > 0; off >>= 1) mx = fmaxf(mx, __shfl_xor(mx, off, 16));
        float ss = expf(acc - mx);
        #pragma unroll
        for (int off = 8; off > 0; off >>= 1) ss += __shfl_xor(ss, off, 16);
        dst[n * 16 + f] = acc - mx - logf(ss);
    } else {
        dst[n * FA + f] = acc;
    }
}

// LPA iteration: FIRST computes one-hot*mask on the fly; SOFTMAX fuses final log_softmax
template <bool FIRST, bool SOFTMAX>
__global__ __launch_bounds__(256) void lpa_kernel(const float* __restrict__ src,
                                                  const int* __restrict__ y,
                                                  const int* __restrict__ mask,
                                                  const int* __restrict__ rowptr,
                                                  const int* __restrict__ srow,
                                                  const float* __restrict__ ew_s,
                                                  float* __restrict__ dst) {
    const int t = threadIdx.x;
    const int nl = t >> 4, f = t & 15;
    const int n = blockIdx.x * 16 + nl;
    float acc = 0.f;
    const int e0 = rowptr[n], e1 = rowptr[n + 1];
    for (int j = e0; j < e1; ++j) {
        const int r = srow[j];
        float v;
        if constexpr (FIRST) v = (mask[r] != 0 && y[r] == f) ? 1.f : 0.f;
        else                 v = src[r * 16 + f];
        acc = fmaf(ew_s[j], v, acc);
    }
    if constexpr (SOFTMAX) {
        float mx = acc;
        #pragma unroll
        for (int off = 8; off > 0; off >>= 1) mx = fmaxf(mx, __shfl_xor(mx, off, 16));
        float ss = expf(acc - mx);
        #pragma unroll
        for (int off = 8; off > 0; off >>= 1) ss += __shfl_xor(ss, off, 16);
        dst[n * 16 + f] = acc - mx - logf(ss);
    } else {
        dst[n * 16 + f] = acc;
    }
}

extern "C" void kernel_launch(void* const* d_in, const int* in_sizes, int n_in,
                              void* d_out, int out_size, void* d_ws, size_t ws_size,
                              hipStream_t stream) {
    const float* x      = (const float*)d_in[0];
    const int*   ei     = (const int*)d_in[1];   // [2*E0] flat: rows then cols
    const int*   y      = (const int*)d_in[2];
    const int*   mask   = (const int*)d_in[3];
    const float* W_edge = (const float*)d_in[4];
    const float* b_edge = (const float*)d_in[5];
    const float* W1 = (const float*)d_in[6];  const float* b1 = (const float*)d_in[7];
    const float* W2 = (const float*)d_in[8];  const float* b2 = (const float*)d_in[9];
    const float* W3 = (const float*)d_in[10]; const float* b3 = (const float*)d_in[11];
    const float* W4 = (const float*)d_in[12]; const float* b4 = (const float*)d_in[13];
    float* out = (float*)d_out;

    // workspace layout
    float* ws     = (float*)d_ws;
    float* ew_raw = ws;                        // E
    float* ew_s   = ew_raw + E_TOT;            // E (CSR order)
    float* deg    = ew_s + E_TOT;              // N
    float* bufA   = deg + N_NODES;             // N*32
    float* bufB   = bufA + N_NODES * HID1;     // N*32
    float* yhA    = bufB + N_NODES * HID1;     // N*16
    float* yhB    = yhA + N_NODES * C_CLS;     // N*16
    int* cnt      = (int*)(yhB + N_NODES * C_CLS); // N
    int* rowptr   = cnt + N_NODES;             // N+1
    int* fillcnt  = rowptr + (N_NODES + 1);    // N
    int* srow     = fillcnt + N_NODES;         // E
    int* eid      = srow + E_TOT;              // E
    int* pos      = eid + E_TOT;               // E

    const int T = 256;
    const int eB = E_TOT / T;       // 64
    const int nB16 = N_NODES * 16 / T;  // 256
    const int nB32 = N_NODES * 32 / T;  // 512

    // --- CSR build (independent of W_edge) ---
    hipMemsetAsync(cnt, 0, N_NODES * sizeof(int), stream);
    csr_count_kernel<<<eB, T, 0, stream>>>(ei, cnt);
    scan_kernel<<<1, T, 0, stream>>>(cnt, rowptr, fillcnt);
    csr_fill_kernel<<<eB, T, 0, stream>>>(ei, rowptr, fillcnt, srow, eid, pos);

    // --- edge weights ---
    row_sum_kernel<<<E_TOT, T, 0, stream>>>(W_edge, b_edge, ew_raw);
    deg_kernel<<<N_NODES / T, T, 0, stream>>>(ew_raw, rowptr, eid, deg);
    scale_kernel<<<eB, T, 0, stream>>>(ei, ew_raw, deg, pos, ew_s);

    // --- GCN: dense1; then fused agg+relu+dense per layer; final agg+softmax ---
    dense1_kernel<<<nB32, T, 0, stream>>>(x, W1, b1, bufA);
    layer_kernel<32, 16, true,  true,  false><<<nB32, T, 0, stream>>>(bufA, rowptr, srow, ew_s, W2, b2, bufB);
    layer_kernel<16, 16, true,  true,  false><<<nB16, T, 0, stream>>>(bufB, rowptr, srow, ew_s, W3, b3, bufA);
    layer_kernel<16, 16, true,  true,  false><<<nB16, T, 0, stream>>>(bufA, rowptr, srow, ew_s, W4, b4, bufB);
    layer_kernel<16, 16, false, false, true ><<<nB16, T, 0, stream>>>(bufB, rowptr, srow, ew_s, nullptr, nullptr, out);

    // --- LPA: 5 gather iterations; one-hot fused into #1, softmax into #5 ---
    lpa_kernel<true,  false><<<nB16, T, 0, stream>>>(nullptr, y, mask, rowptr, srow, ew_s, yhA);
    lpa_kernel<false, false><<<nB16, T, 0, stream>>>(yhA, y, mask, rowptr, srow, ew_s, yhB);
    lpa_kernel<false, false><<<nB16, T, 0, stream>>>(yhB, y, mask, rowptr, srow, ew_s, yhA);
    lpa_kernel<false, false><<<nB16, T, 0, stream>>>(yhA, y, mask, rowptr, srow, ew_s, yhB);
    lpa_kernel<false, true ><<<nB16, T, 0, stream>>>(yhB, y, mask, rowptr, srow, ew_s, out + (size_t)N_NODES * C_CLS);
}